// Round 1
// baseline (342.546 us; speedup 1.0000x reference)
//
#include <hip/hip_runtime.h>
#include <hip/hip_bf16.h>

#define KK 9
#define PADK 4
#define CIN 64
#define COUT 64
#define LSEQ 131072
#define NB 4
#define TILEL 128         // l-extent of a block tile
#define XROWS 136         // TILEL + KK - 1
#define XRS 72            // xt row stride (bf16); 144 B rows -> uniform 8/bank reads
#define NTILES 1024       // LSEQ / TILEL
#define NPART 64
#define TPB 4             // tiles per (persistent) block
#define GRIDC (NB * NTILES / TPB)   // 1024 blocks -> ~3/CU resident, pipelined

typedef __attribute__((ext_vector_type(8))) short v8s;
typedef __attribute__((ext_vector_type(4))) float v4f;

__device__ __forceinline__ unsigned short f2bf(float f) {
  __hip_bfloat16 h = __float2bfloat16(f);
  return *reinterpret_cast<unsigned short*>(&h);
}
__device__ __forceinline__ float bf2f(unsigned short s) {
  return __uint_as_float(((unsigned)s) << 16);
}

__device__ __forceinline__ void store_o(float* p, float v) { *p = v; }
__device__ __forceinline__ void store_o(__hip_bfloat16* p, float v) { *p = __float2bfloat16(v); }

// ---------------------------------------------------------------------------
// Repack W[Cout][Cin][K] fp32 -> bf16 A-fragments for mfma_f32_16x16x32_bf16,
// pre-swizzled: frag (k, s, mblk) is 1024 contiguous bytes, lane-major.
// ---------------------------------------------------------------------------
__global__ void wtrans_kernel(const float* __restrict__ W, v8s* __restrict__ Wt) {
  int t = blockIdx.x * 256 + threadIdx.x;
  if (t >= KK * 2 * 4 * 64) return;
  int lane = t & 63;
  int frag = t >> 6;
  int mblk = frag & 3;
  int s    = (frag >> 2) & 1;
  int k    = frag >> 3;
  int m = lane & 15, q = lane >> 4;
  int o = mblk * 16 + m;
  union { v8s v; unsigned short h[8]; } u;
#pragma unroll
  for (int j = 0; j < 8; ++j) {
    int c = 32 * s + q * 8 + j;
    u.h[j] = f2bf(W[(o * CIN + c) * KK + k]);
  }
  Wt[t] = u.v;
}

// ---------------------------------------------------------------------------
// Weighted conv via MFMA, telescoped per-k GEMM decomposition.
// R5: persistent blocks (TPB=4 tiles each) with LDS double-buffer and
// async-stage split: tile t+1's global loads are issued BEFORE a raw
// s_barrier (only lgkmcnt drained), so HBM latency/BW overlaps tile t's
// MFMA+LDS compute instead of serializing per tile.
// Coord/gaussian work is spread over all 256 threads (thread = (n, k-half)).
// ---------------------------------------------------------------------------
template <typename OutT>
__global__ __launch_bounds__(256, 3)
void conv_kernel(const float* __restrict__ x, const float* __restrict__ coords,
                 const v8s* __restrict__ Wt, OutT* __restrict__ cv,
                 float* __restrict__ stat_sum, float* __restrict__ stat_sq) {
  __shared__ __align__(16) __hip_bfloat16 xt[2][XROWS][XRS]; // 39168 B
  __shared__ float wt[2][KK][TILEL];                         //  9216 B

  const int tid  = threadIdx.x;
  const int wv   = tid >> 6;
  const int wo   = wv & 1;                    // o-half (32 rows)
  const int wl   = wv >> 1;                   // l-half (64 cols)
  const int lane = tid & 63;
  const int m = lane & 15;
  const int q = lane >> 4;

  const int bid = blockIdx.x;                 // 0..1023
  const int b   = bid >> 8;                   // 256 blocks per batch
  const int t0  = (bid & 255) * TPB;          // first tile (consecutive -> halo L2 reuse)
  const float* xb = x + (b * CIN) * LSEQ;
  const float* cb = coords + (b * 3) * LSEQ;
  OutT* outb = cv + (b * COUT) * LSEQ;

  // staging thread roles
  const int cg = tid & 7, lc = tid >> 3, c8 = cg * 8;   // x main stage
  const int cn = tid >> 1;                    // coord n (0..127)
  const int khalf = tid & 1;                  // k-half: w[0..4] or w[4..8]
  const int k0 = khalf * 4;

  // prefetch registers (live across the compute phase)
  float4 f[8];                                // x main: 8 channels x 4 l
  float4 hx;                                  // halo (tid<128)
  float sx, sy, sz;                           // center coords
  float cxk[5], cyk[5], czk[5];               // neighbor coords (5 ks)

  auto prefetch = [&](int tile) {
    const int l0 = tile * TILEL;
#pragma unroll
    for (int t = 0; t < 8; ++t)
      f[t] = *(const float4*)(xb + (c8 + t) * LSEQ + l0 + 4 * lc);
    if (tid < 128) {
      int side = tid >> 6, c = tid & 63;
      hx = make_float4(0.f, 0.f, 0.f, 0.f);
      if (side == 0) {
        if (tile != 0) hx = *(const float4*)(xb + c * LSEQ + l0 - 4);
      } else {
        if (tile != NTILES - 1) hx = *(const float4*)(xb + c * LSEQ + l0 + TILEL);
      }
    }
    sx = cb[l0 + cn];
    sy = cb[LSEQ + l0 + cn];
    sz = cb[2 * LSEQ + l0 + cn];
#pragma unroll
    for (int i = 0; i < 5; ++i) {
      int l = l0 + cn + (k0 + i) - PADK;
      float cx = 0.f, cy = 0.f, cz = 0.f;
      if ((unsigned)l < (unsigned)LSEQ) {     // zero-pad like jnp.pad
        cx = cb[l]; cy = cb[LSEQ + l]; cz = cb[2 * LSEQ + l];
      }
      cxk[i] = cx; cyk[i] = cy; czk[i] = cz;
    }
  };

  prefetch(t0);

#pragma unroll 1
  for (int ti = 0; ti < TPB; ++ti) {
    const int tile = t0 + ti;
    const int l0 = tile * TILEL;
    const int cur = ti & 1;

    // ---- consume prefetched regs -> LDS buf[cur] ----
    {
      const float* fp = (const float*)&f[0];
#pragma unroll
      for (int j = 0; j < 4; ++j) {
        union { v8s v; unsigned short h[8]; } u;
#pragma unroll
        for (int t = 0; t < 8; ++t) u.h[t] = f2bf(fp[4 * t + j]);
        *(v8s*)&xt[cur][4 + 4 * lc + j][c8] = u.v;
      }
      if (tid < 128) {
        int side = tid >> 6, c = tid & 63;
        int rb = side ? (TILEL + PADK) : 0;
        xt[cur][rb + 0][c] = __float2bfloat16(hx.x);
        xt[cur][rb + 1][c] = __float2bfloat16(hx.y);
        xt[cur][rb + 2][c] = __float2bfloat16(hx.z);
        xt[cur][rb + 3][c] = __float2bfloat16(hx.w);
      }
      float w5[5];
#pragma unroll
      for (int i = 0; i < 5; ++i) {
        float dx = cxk[i] - sx, dy = cyk[i] - sy, dz = czk[i] - sz;
        w5[i] = __expf(-0.5f * (dx * dx + dy * dy + dz * dz));
      }
      // telescoping delta weights: d[k] = w[k] - w[k+1], d[8] = w[8]
      if (khalf == 0) {
#pragma unroll
        for (int i = 0; i < 4; ++i) wt[cur][i][cn] = w5[i] - w5[i + 1];
      } else {
#pragma unroll
        for (int i = 0; i < 4; ++i) wt[cur][4 + i][cn] = w5[i] - w5[i + 1];
        wt[cur][8][cn] = w5[4];
      }
    }

    // ---- issue next tile's global loads; they stay in flight across the
    //      barrier (raw s_barrier: no vmcnt drain) and hide under compute ----
    if (ti + 1 < TPB) prefetch(tile + 1);

    asm volatile("s_waitcnt lgkmcnt(0)" ::: "memory");
    __builtin_amdgcn_s_barrier();

    // ---- MFMA main loop (reads buf[cur]) ----
    v4f y[2][4], tot[2][4];
#pragma unroll
    for (int i = 0; i < 2; ++i)
#pragma unroll
      for (int j = 0; j < 4; ++j) {
        y[i][j]   = (v4f){0.f, 0.f, 0.f, 0.f};
        tot[i][j] = (v4f){0.f, 0.f, 0.f, 0.f};
      }

    const v8s* wp = Wt + (wo * 2) * 64 + lane;

#pragma unroll 1
    for (int k = 0; k < KK; ++k) {
#pragma unroll
      for (int s = 0; s < 2; ++s) {
        v8s a0 = wp[k * 512 + s * 256];
        v8s a1 = wp[k * 512 + s * 256 + 64];
#pragma unroll
        for (int nbq = 0; nbq < 4; ++nbq) {
          v8s bf = *(const v8s*)&xt[cur][wl * 64 + nbq * 16 + m + k][q * 8 + 32 * s];
          y[0][nbq] = __builtin_amdgcn_mfma_f32_16x16x32_bf16(a0, bf, y[0][nbq], 0, 0, 0);
          y[1][nbq] = __builtin_amdgcn_mfma_f32_16x16x32_bf16(a1, bf, y[1][nbq], 0, 0, 0);
        }
      }
      // telescoping accumulate
#pragma unroll
      for (int nbq = 0; nbq < 4; ++nbq) {
        float d = wt[cur][k][wl * 64 + nbq * 16 + m];
#pragma unroll
        for (int mb = 0; mb < 2; ++mb)
#pragma unroll
          for (int r = 0; r < 4; ++r)
            tot[mb][nbq][r] = __builtin_fmaf(d, y[mb][nbq][r], tot[mb][nbq][r]);
      }
    }

    // ---- epilogue: store conv result + per-channel sum/sumsq partials ----
    const int part = tile & (NPART - 1);
#pragma unroll
    for (int mb = 0; mb < 2; ++mb) {
#pragma unroll
      for (int r = 0; r < 4; ++r) {
        int o = wo * 32 + mb * 16 + q * 4 + r;   // C-layout: row = q*4 + reg
        float s1 = 0.f, s2 = 0.f;
#pragma unroll
        for (int nbq = 0; nbq < 4; ++nbq) {
          float v = tot[mb][nbq][r];
          s1 += v;
          s2 += v * v;
          store_o(&outb[o * LSEQ + l0 + wl * 64 + nbq * 16 + m], v); // col = lane&15
        }
#pragma unroll
        for (int off = 1; off < 16; off <<= 1) {
          s1 += __shfl_xor(s1, off, 64);
          s2 += __shfl_xor(s2, off, 64);
        }
        if (m == 0) {
          atomicAdd(&stat_sum[part * COUT + o], s1);
          atomicAdd(&stat_sq [part * COUT + o], s2);
        }
      }
    }
    // NOTE: one barrier per tile suffices: buf[cur^1] written next iter was
    // last read two iters ago, fenced by the intervening barrier (dbuf).
  }
}

// ---------------------------------------------------------------------------
// BN finalize: scale = gamma*rsqrt(var+eps), shift = beta - mean*scale.
// (Conv bias cancels exactly under training-mode BN, so it is skipped.)
// ---------------------------------------------------------------------------
__global__ void finalize_kernel(const float* __restrict__ stat_sum,
                                const float* __restrict__ stat_sq,
                                const float* __restrict__ gamma,
                                const float* __restrict__ beta,
                                float* __restrict__ ss) {
  int o = threadIdx.x;
  float s1 = 0.f, s2 = 0.f;
  for (int p = 0; p < NPART; ++p) {
    s1 += stat_sum[p * COUT + o];
    s2 += stat_sq [p * COUT + o];
  }
  const float invN = 1.0f / (float)(NB * LSEQ);
  float mean = s1 * invN;
  float var  = s2 * invN - mean * mean;   // biased, matches jnp.var
  float sc = gamma[o] * rsqrtf(var + 1e-5f);
  ss[o]        = sc;
  ss[COUT + o] = beta[o] - mean * sc;
}

// ---- BN apply + ReLU; one block = 2048 contiguous elems in one channel ----
__global__ __launch_bounds__(256)
void scale_f32_kernel(float* __restrict__ data, const float* __restrict__ ss) {
  const int blk = blockIdx.x;
  const int ch = (blk >> 6) & 63;   // L/2048 = 64 blocks per channel
  const float sc = ss[ch];
  const float sh = ss[COUT + ch];
  const int base = blk * 2048 + threadIdx.x * 8;
  float4 a = *(float4*)(data + base);
  float4 b = *(float4*)(data + base + 4);
  a.x = fmaxf(fmaf(a.x, sc, sh), 0.f);
  a.y = fmaxf(fmaf(a.y, sc, sh), 0.f);
  a.z = fmaxf(fmaf(a.z, sc, sh), 0.f);
  a.w = fmaxf(fmaf(a.w, sc, sh), 0.f);
  b.x = fmaxf(fmaf(b.x, sc, sh), 0.f);
  b.y = fmaxf(fmaf(b.y, sc, sh), 0.f);
  b.z = fmaxf(fmaf(b.z, sc, sh), 0.f);
  b.w = fmaxf(fmaf(b.w, sc, sh), 0.f);
  *(float4*)(data + base)     = a;
  *(float4*)(data + base + 4) = b;
}

__global__ __launch_bounds__(256)
void scale_bf16_kernel(const __hip_bfloat16* __restrict__ cvin,
                       const float* __restrict__ ss, float* __restrict__ out) {
  const int blk = blockIdx.x;
  const int ch = (blk >> 6) & 63;
  const float sc = ss[ch];
  const float sh = ss[COUT + ch];
  const int base = blk * 2048 + threadIdx.x * 8;
  union { v8s v; unsigned short h[8]; } u;
  u.v = *(const v8s*)(cvin + base);
  float r[8];
#pragma unroll
  for (int i = 0; i < 8; ++i)
    r[i] = fmaxf(fmaf(bf2f(u.h[i]), sc, sh), 0.f);
  *(float4*)(out + base)     = make_float4(r[0], r[1], r[2], r[3]);
  *(float4*)(out + base + 4) = make_float4(r[4], r[5], r[6], r[7]);
}

extern "C" void kernel_launch(void* const* d_in, const int* in_sizes, int n_in,
                              void* d_out, int out_size, void* d_ws, size_t ws_size,
                              hipStream_t stream) {
  const float* x      = (const float*)d_in[0];
  const float* coords = (const float*)d_in[1];
  const float* W      = (const float*)d_in[2];
  // d_in[3] = bias: cancels under training-mode BatchNorm; unused.
  const float* gamma  = (const float*)d_in[4];
  const float* beta   = (const float*)d_in[5];
  float* out = (float*)d_out;
  char* ws = (char*)d_ws;

  float* stat_sum = (float*)(ws);            // 64*64 f32
  float* stat_sq  = (float*)(ws + 16384);    // 64*64 f32
  float* ss       = (float*)(ws + 32768);    // 128 f32
  v8s*   Wt       = (v8s*)(ws + 40960);      // 73728 B
  __hip_bfloat16* scratch = (__hip_bfloat16*)(ws + 131072); // 64 MiB (optional)

  const size_t need_bf16 = (size_t)131072 + (size_t)NB * COUT * LSEQ * 2;
  const bool bf16_path = ws_size >= need_bf16;

  hipMemsetAsync(ws, 0, 32768, stream);
  wtrans_kernel<<<18, 256, 0, stream>>>(W, Wt);

  if (bf16_path) {
    conv_kernel<__hip_bfloat16><<<GRIDC, 256, 0, stream>>>(
        x, coords, Wt, scratch, stat_sum, stat_sq);
    finalize_kernel<<<1, COUT, 0, stream>>>(stat_sum, stat_sq, gamma, beta, ss);
    scale_bf16_kernel<<<(NB * COUT * (LSEQ / 2048)), 256, 0, stream>>>(scratch, ss, out);
  } else {
    conv_kernel<float><<<GRIDC, 256, 0, stream>>>(
        x, coords, Wt, out, stat_sum, stat_sq);
    finalize_kernel<<<1, COUT, 0, stream>>>(stat_sum, stat_sq, gamma, beta, ss);
    scale_f32_kernel<<<(NB * COUT * (LSEQ / 2048)), 256, 0, stream>>>(out, ss);
  }
}